// Round 1
// baseline (69.883 us; speedup 1.0000x reference)
//
#include <hip/hip_runtime.h>
#include <stdint.h>

typedef unsigned short ushort_t;
typedef short short8 __attribute__((ext_vector_type(8)));
typedef float f32x4 __attribute__((ext_vector_type(4)));

#define CIN   64
#define COUT  128
#define BATCH 16
#define LPIX  1024               // 32*32
#define NTOT  (BATCH*LPIX)       // 16384
#define KTOT  5184               // 9 * 576
#define C2N   576                // CIN*9 features
#define PIXN  (BATCH*34*34)      // 18496 padded pixels
#define WROW  KTOT               // ushorts per Cout row

// workspace layout (bytes)
#define FEAT_BYTES (PIXN*C2N*2)            // 21,307,392
#define W_OFF      FEAT_BYTES
#define W_BYTES    (COUT*KTOT*2)           // 1,327,104
#define PART_OFF   (W_OFF + W_BYTES)
#define PART_BYTES (NTOT*COUT*4)           // 8,388,608
#define WS_NEED    ((size_t)(PART_OFF + PART_BYTES))

__device__ __forceinline__ ushort_t to_bf16(float f) {
  union { float f; uint32_t u; } v; v.f = f;
  uint32_t r = (v.u + 0x7fffu + ((v.u >> 16) & 1u)) >> 16;
  return (ushort_t)r;
}

// H_0..H_7 (physicists') of x, plus silu(x) at [8]
__device__ __forceinline__ void basis9(float x, float* o) {
  float hm = 1.f, h = 2.f * x;
  o[0] = hm; o[1] = h;
#pragma unroll
  for (int n = 1; n < 7; ++n) {
    float nx = 2.f * x * h - 2.f * (float)n * hm;
    hm = h; h = nx;
    o[n + 1] = nx;
  }
  o[8] = x / (1.f + __expf(-x));
}

__device__ __forceinline__ void load16(const void* g, void* l) {
  __builtin_amdgcn_global_load_lds(
      (const __attribute__((address_space(1))) uint32_t*)g,
      (__attribute__((address_space(3))) uint32_t*)l, 16, 0, 0);
}

// ---------------- feature map: feat[pix(b,34,34)][i*9+f] bf16 -------------
__global__ void feat_kernel(const float* __restrict__ x, ushort_t* __restrict__ feat) {
  const int t = threadIdx.x;
  const int lane = t & 63;                      // = cin index i
  const int pg = blockIdx.x * 4 + (t >> 6);     // padded pixel id
  if (pg >= PIXN) return;
  const int xx = pg % 34;
  const int rest = pg / 34;
  const int yy = rest % 34;
  const int bb = rest / 34;
  float v = 0.f;
  if (xx >= 1 && xx <= 32 && yy >= 1 && yy <= 32)
    v = x[((bb * CIN + lane) * 32 + (yy - 1)) * 32 + (xx - 1)];
  float o[9];
  basis9(v, o);
  ushort_t* dst = feat + (size_t)pg * C2N + lane * 9;
#pragma unroll
  for (int f = 0; f < 9; ++f) dst[f] = to_bf16(o[f]);
}

// ---------------- weight matrix, pre-swizzled for global_load_lds ---------
// logical W[m][k], k = kk*576 + i*9 + f ; storage chunk (k/8) xored with m&7
__global__ void prep_w_kernel(const float* __restrict__ wb, const float* __restrict__ wsp,
                              const float* __restrict__ cc, ushort_t* __restrict__ W) {
  const int idx = blockIdx.x * 256 + threadIdx.x;
  if (idx >= COUT * KTOT) return;
  const int m = idx / KTOT;
  const int k = idx - m * KTOT;
  const int kk = k / C2N;
  const int r = k - kk * C2N;
  const int i = r / 9;
  const int f = r - i * 9;
  const int base = (i * COUT + m) * 9 + kk;
  const float val = (f < 8) ? wsp[base] * cc[base * 8 + f] : wb[base];
  const int slot = (k >> 3) & 7;
  const int e = k & 7;
  const int sidx = m * WROW + (k >> 6) * 64 + ((slot ^ (m & 7)) << 3) + e;
  W[sidx] = to_bf16(val);
}

// ---------------- GEMM: out[n][m] += W[m][k] * feat_im2col[k][n] ----------
__global__ __launch_bounds__(256, 2) void gemm_kernel(const ushort_t* __restrict__ feat,
                                                      const ushort_t* __restrict__ W,
                                                      float* __restrict__ out,
                                                      float* __restrict__ part) {
  __shared__ ushort_t Ab[2][8192];   // [m=128][k=64], 128B rows, slot-swizzled
  __shared__ ushort_t Bb[2][8192];   // [n=128][k=64], same swizzle
  const int t = threadIdx.x;
  const int lane = t & 63;
  const int wave = t >> 6;
  const int wm = wave >> 1, wn = wave & 1;
  const int nb = blockIdx.x & 127;
  const int slice = blockIdx.x >> 7;
  const int s_lo = slice ? 40 : 0;
  const int s_hi = slice ? 81 : 40;

  const char* Wb = (const char*)W;
  const char* Fb = (const char*)feat;

  f32x4 acc[4][4];
#pragma unroll
  for (int a = 0; a < 4; ++a)
#pragma unroll
    for (int b = 0; b < 4; ++b) acc[a][b] = (f32x4)0.f;

  auto stage = [&](int p, int s) {
    // A tile: 128 rows x 128B, already swizzled in global storage
#pragma unroll
    for (int q = 0; q < 4; ++q) {
      const int idx16 = q * 256 + t;
      const int m = idx16 >> 3, ccn = idx16 & 7;
      load16(Wb + m * (WROW * 2) + s * 128 + ccn * 16, &Ab[p][idx16 * 8]);
    }
    // B tile: gather rows of feat, pre-swizzle on the global side
    const int k0 = s * 64;
#pragma unroll
    for (int q = 0; q < 4; ++q) {
      const int idx16 = q * 256 + t;
      const int nl = idx16 >> 3, ccn = idx16 & 7;
      const int lc = ccn ^ (nl & 7);         // logical 8-k chunk
      const int k = k0 + lc * 8;
      const int kk = k / C2N;                // spatial tap 0..8
      const int c2 = k - kk * C2N;           // channel 0..575 (8-aligned)
      const int dy = kk / 3;
      const int dx = kk - dy * 3;
      const int n = nb * 128 + nl;
      const int pix = ((n >> 10) * 34 + ((n >> 5) & 31) + dy) * 34 + (n & 31) + dx;
      load16(Fb + (size_t)pix * (C2N * 2) + c2 * 2, &Bb[p][idx16 * 8]);
    }
  };

  auto compute = [&](int p) {
#pragma unroll
    for (int ks = 0; ks < 2; ++ks) {
      short8 av[4], bv[4];
#pragma unroll
      for (int mf = 0; mf < 4; ++mf) {
        const int row = wm * 64 + mf * 16 + (lane & 15);
        const int slot = ks * 4 + (lane >> 4);
        av[mf] = *(const short8*)&Ab[p][row * 64 + ((slot ^ (row & 7)) << 3)];
      }
#pragma unroll
      for (int nf = 0; nf < 4; ++nf) {
        const int row = wn * 64 + nf * 16 + (lane & 15);
        const int slot = ks * 4 + (lane >> 4);
        bv[nf] = *(const short8*)&Bb[p][row * 64 + ((slot ^ (row & 7)) << 3)];
      }
#pragma unroll
      for (int mf = 0; mf < 4; ++mf)
#pragma unroll
        for (int nf = 0; nf < 4; ++nf)
          acc[mf][nf] = __builtin_amdgcn_mfma_f32_16x16x32_bf16(av[mf], bv[nf],
                                                                acc[mf][nf], 0, 0, 0);
    }
  };

  stage(0, s_lo);
  __syncthreads();
  for (int s = s_lo; s < s_hi; ++s) {
    const int p = (s - s_lo) & 1;
    if (s + 1 < s_hi) stage(p ^ 1, s + 1);
    compute(p);
    __syncthreads();
  }

  float* dst = slice ? part : out;
#pragma unroll
  for (int mf = 0; mf < 4; ++mf)
#pragma unroll
    for (int nf = 0; nf < 4; ++nf)
#pragma unroll
      for (int rg = 0; rg < 4; ++rg) {
        const int m = wm * 64 + mf * 16 + (lane >> 4) * 4 + rg;
        const int n = nb * 128 + wn * 64 + nf * 16 + (lane & 15);
        const int bb = n >> 10, ll = n & 1023;
        dst[(bb * COUT + m) * LPIX + ll] = acc[mf][nf][rg];
      }
}

__global__ void add_kernel(float* __restrict__ out, const float* __restrict__ part) {
  const int i = (blockIdx.x * 256 + threadIdx.x) * 4;
  f32x4 a = *(const f32x4*)&out[i];
  const f32x4 b = *(const f32x4*)&part[i];
  a += b;
  *(f32x4*)&out[i] = a;
}

// ---------------- fallback (only if ws too small): direct evaluation -----
__global__ void naive_kernel(const float* __restrict__ x, const float* __restrict__ wb,
                             const float* __restrict__ wsp, const float* __restrict__ cc,
                             float* __restrict__ out) {
  const int idx = blockIdx.x * 256 + threadIdx.x;
  if (idx >= BATCH * COUT * LPIX) return;
  const int l = idx & 1023, o = (idx >> 10) & 127, b = idx >> 17;
  const int h = l >> 5, w = l & 31;
  float acc = 0.f;
  for (int i = 0; i < CIN; ++i)
    for (int kk = 0; kk < 9; ++kk) {
      const int yy = h + kk / 3 - 1, xx = w + kk % 3 - 1;
      const float v = (yy >= 0 && yy < 32 && xx >= 0 && xx < 32)
                          ? x[((b * CIN + i) * 32 + yy) * 32 + xx] : 0.f;
      float ftr[9];
      basis9(v, ftr);
      const int base = (i * COUT + o) * 9 + kk;
      const float* cp = cc + base * 8;
      float dot = 0.f;
#pragma unroll
      for (int f = 0; f < 8; ++f) dot += cp[f] * ftr[f];
      acc += wsp[base] * dot + wb[base] * ftr[8];
    }
  out[idx] = acc;
}

extern "C" void kernel_launch(void* const* d_in, const int* in_sizes, int n_in,
                              void* d_out, int out_size, void* d_ws, size_t ws_size,
                              hipStream_t stream) {
  const float* x  = (const float*)d_in[0];
  const float* wb = (const float*)d_in[1];
  const float* wsp = (const float*)d_in[2];
  const float* cc = (const float*)d_in[3];
  float* out = (float*)d_out;

  if (ws_size < WS_NEED) {
    naive_kernel<<<(BATCH * COUT * LPIX + 255) / 256, 256, 0, stream>>>(x, wb, wsp, cc, out);
    return;
  }

  char* ws = (char*)d_ws;
  ushort_t* feat = (ushort_t*)ws;
  ushort_t* W    = (ushort_t*)(ws + W_OFF);
  float* part    = (float*)(ws + PART_OFF);

  feat_kernel<<<PIXN / 4, 256, 0, stream>>>(x, feat);
  prep_w_kernel<<<(COUT * KTOT) / 256, 256, 0, stream>>>(wb, wsp, cc, W);
  gemm_kernel<<<256, 256, 0, stream>>>(feat, W, out, part);
  add_kernel<<<NTOT * COUT / (256 * 4), 256, 0, stream>>>(out, part);
}

// Round 2
// 51.306 us; speedup vs baseline: 1.3621x; 1.3621x over previous
//
#include <hip/hip_runtime.h>
#include <stdint.h>

typedef unsigned short ushort_t;
typedef short short8 __attribute__((ext_vector_type(8)));
typedef float f32x4 __attribute__((ext_vector_type(4)));

#define CIN   64
#define COUT  128
#define BATCH 16
#define LPIX  1024               // 32*32
#define NTOT  (BATCH*LPIX)       // 16384
#define KTOT  5184               // 9 * 576
#define C2N   576                // CIN*9 features
#define PIXN  (BATCH*34*34)      // 18496 padded pixels
#define WROW  KTOT               // ushorts per Cout row
#define NSTEP 81                 // 9 c2-slices x 9 taps
#define PART_ELEMS (NTOT*COUT)   // 2,097,152

// workspace layout (bytes)
#define FEAT_BYTES (PIXN*C2N*2)            // 21,307,392
#define W_OFF      FEAT_BYTES
#define W_BYTES    (COUT*KTOT*2)           // 1,327,104
#define PART_OFF   (W_OFF + W_BYTES)
#define PART_BYTES (PART_ELEMS*4)          // 8,388,608
#define WS_NEED2   ((size_t)(PART_OFF + 1*PART_BYTES))
#define WS_NEED4   ((size_t)(PART_OFF + 3*PART_BYTES))

__device__ __forceinline__ ushort_t to_bf16(float f) {
  union { float f; uint32_t u; } v; v.f = f;
  uint32_t r = (v.u + 0x7fffu + ((v.u >> 16) & 1u)) >> 16;
  return (ushort_t)r;
}

// H_0..H_7 (physicists') of x, plus silu(x) at [8]
__device__ __forceinline__ void basis9(float x, float* o) {
  float hm = 1.f, h = 2.f * x;
  o[0] = hm; o[1] = h;
#pragma unroll
  for (int n = 1; n < 7; ++n) {
    float nx = 2.f * x * h - 2.f * (float)n * hm;
    hm = h; h = nx;
    o[n + 1] = nx;
  }
  o[8] = x / (1.f + __expf(-x));
}

__device__ __forceinline__ void load16(const void* g, void* l) {
  __builtin_amdgcn_global_load_lds(
      (const __attribute__((address_space(1))) uint32_t*)g,
      (__attribute__((address_space(3))) uint32_t*)l, 16, 0, 0);
}

// ---------------- feature map: feat[pix(b,34,34)][i*9+f] bf16 -------------
__global__ void feat_kernel(const float* __restrict__ x, ushort_t* __restrict__ feat) {
  const int t = threadIdx.x;
  const int lane = t & 63;                      // = cin index i
  const int pg = blockIdx.x * 4 + (t >> 6);     // padded pixel id
  if (pg >= PIXN) return;
  const int xx = pg % 34;
  const int rest = pg / 34;
  const int yy = rest % 34;
  const int bb = rest / 34;
  float v = 0.f;
  if (xx >= 1 && xx <= 32 && yy >= 1 && yy <= 32)
    v = x[((bb * CIN + lane) * 32 + (yy - 1)) * 32 + (xx - 1)];
  float o[9];
  basis9(v, o);
  ushort_t* dst = feat + (size_t)pg * C2N + lane * 9;
#pragma unroll
  for (int f = 0; f < 9; ++f) dst[f] = to_bf16(o[f]);
}

// ---------------- weight matrix, pre-swizzled for global_load_lds ---------
// logical W[m][k], k = kk*576 + i*9 + f ; storage chunk (k/8) xored with m&7
__global__ void prep_w_kernel(const float* __restrict__ wb, const float* __restrict__ wsp,
                              const float* __restrict__ cc, ushort_t* __restrict__ W) {
  const int idx = blockIdx.x * 256 + threadIdx.x;
  if (idx >= COUT * KTOT) return;
  const int m = idx / KTOT;
  const int k = idx - m * KTOT;
  const int kk = k / C2N;
  const int r = k - kk * C2N;
  const int i = r / 9;
  const int f = r - i * 9;
  const int base = (i * COUT + m) * 9 + kk;
  const float val = (f < 8) ? wsp[base] * cc[base * 8 + f] : wb[base];
  const int slot = (k >> 3) & 7;
  const int e = k & 7;
  const int sidx = m * WROW + (k >> 6) * 64 + ((slot ^ (m & 7)) << 3) + e;
  W[sidx] = to_bf16(val);
}

// ---------------- GEMM with halo-reuse B staging --------------------------
// out[n][m] = sum_k W[m][k] * feat[pix(n,tap)][c2]
// K-order: c2-slice (64 feats) outer, 3x3 tap inner; halo staged once/slice.
template <int KS>
__global__ __launch_bounds__(256, 2) void gemm_kernel(const ushort_t* __restrict__ feat,
                                                      const ushort_t* __restrict__ W,
                                                      float* __restrict__ out,
                                                      float* __restrict__ part) {
  __shared__ ushort_t Ab[2][8192];     // [m=128][k=64], slot-swizzled, dbuf
  __shared__ ushort_t Hb[1792 * 8];    // halo: 224 px x 64 feats (204 used)
  const int t = threadIdx.x;
  const int lane = t & 63;
  const int wave = t >> 6;
  const int wm = wave >> 1, wn = wave & 1;

  // XCD-chunked remap, nb-major: consecutive logicals share the N-tile.
  const int logical = (blockIdx.x & 7) * (gridDim.x >> 3) + (blockIdx.x >> 3);
  const int nb = logical / KS;
  const int slice = logical - nb * KS;
  const int lo = (slice * NSTEP) / KS;
  const int hi = ((slice + 1) * NSTEP) / KS;

  const int b  = nb >> 3;               // image
  const int y0 = (nb & 7) * 4;          // first (unpadded) row; padded rows y0..y0+5
  const int pixbase = (b * 34 + y0) * 34;

  const char* Wb = (const char*)W;
  const char* Fb = (const char*)feat;

  f32x4 acc[4][4];
#pragma unroll
  for (int a = 0; a < 4; ++a)
#pragma unroll
    for (int c = 0; c < 4; ++c) acc[a][c] = (f32x4)0.f;

  auto stage_halo = [&](int c2s) {
    const char* base = Fb + (size_t)pixbase * (C2N * 2) + c2s * 128;
#pragma unroll
    for (int it = 0; it < 7; ++it) {
      const int q = it * 256 + t;           // chunk id, 224 px x 8 chunks
      const int hp = q >> 3, sl = q & 7;
      load16(base + hp * (C2N * 2) + ((sl ^ (hp & 7)) << 4), &Hb[q * 8]);
    }
  };

  auto stageA = [&](int p, int c2s, int kk) {
    const int c64 = kk * 9 + c2s;           // 64-wide K-chunk index in W rows
#pragma unroll
    for (int q = 0; q < 4; ++q) {
      const int idx16 = q * 256 + t;
      const int m = idx16 >> 3, ccn = idx16 & 7;
      load16(Wb + m * (WROW * 2) + c64 * 128 + ccn * 16, &Ab[p][idx16 * 8]);
    }
  };

  auto compute = [&](int p, int dy, int dx) {
#pragma unroll
    for (int ks = 0; ks < 2; ++ks) {
      short8 av[4], bv[4];
      const int slot = ks * 4 + (lane >> 4);
#pragma unroll
      for (int mf = 0; mf < 4; ++mf) {
        const int row = wm * 64 + mf * 16 + (lane & 15);
        av[mf] = *(const short8*)&Ab[p][row * 64 + ((slot ^ (row & 7)) << 3)];
      }
#pragma unroll
      for (int nf = 0; nf < 4; ++nf) {
        const int nl = wn * 64 + nf * 16 + (lane & 15);
        const int hp = ((nl >> 5) + dy) * 34 + (nl & 31) + dx;
        bv[nf] = *(const short8*)&Hb[hp * 64 + ((slot ^ (hp & 7)) << 3)];
      }
#pragma unroll
      for (int mf = 0; mf < 4; ++mf)
#pragma unroll
        for (int nf = 0; nf < 4; ++nf)
          acc[mf][nf] = __builtin_amdgcn_mfma_f32_16x16x32_bf16(av[mf], bv[nf],
                                                                acc[mf][nf], 0, 0, 0);
    }
  };

  int c2s = lo / 9;
  int kk  = lo - c2s * 9;
  stage_halo(c2s);
  stageA(0, c2s, kk);
  __syncthreads();
  int p = 0;
  for (int s = lo; s < hi; ++s) {
    int nkk = kk + 1, nc2s = c2s;
    bool newhalo = false;
    if (nkk == 9) { nkk = 0; ++nc2s; newhalo = true; }
    if (s + 1 < hi) stageA(p ^ 1, nc2s, nkk);
    const int dy = kk / 3, dx = kk - dy * 3;
    compute(p, dy, dx);
    __syncthreads();
    if (s + 1 < hi && newhalo) {
      stage_halo(nc2s);
      __syncthreads();
    }
    kk = nkk; c2s = nc2s; p ^= 1;
  }

  float* dst = slice ? (part + (size_t)(slice - 1) * PART_ELEMS) : out;
#pragma unroll
  for (int mf = 0; mf < 4; ++mf)
#pragma unroll
    for (int nf = 0; nf < 4; ++nf)
#pragma unroll
      for (int rg = 0; rg < 4; ++rg) {
        const int m = wm * 64 + mf * 16 + (lane >> 4) * 4 + rg;
        const int n = nb * 128 + wn * 64 + nf * 16 + (lane & 15);
        const int bb = n >> 10, ll = n & 1023;
        dst[(bb * COUT + m) * LPIX + ll] = acc[mf][nf][rg];
      }
}

template <int NP>
__global__ void add_kernel(float* __restrict__ out, const float* __restrict__ part) {
  const int i = (blockIdx.x * 256 + threadIdx.x) * 4;
  f32x4 a = *(const f32x4*)&out[i];
#pragma unroll
  for (int j = 0; j < NP; ++j)
    a += *(const f32x4*)&part[(size_t)j * PART_ELEMS + i];
  *(f32x4*)&out[i] = a;
}

// ---------------- fallback (only if ws too small): direct evaluation -----
__global__ void naive_kernel(const float* __restrict__ x, const float* __restrict__ wb,
                             const float* __restrict__ wsp, const float* __restrict__ cc,
                             float* __restrict__ out) {
  const int idx = blockIdx.x * 256 + threadIdx.x;
  if (idx >= BATCH * COUT * LPIX) return;
  const int l = idx & 1023, o = (idx >> 10) & 127, b = idx >> 17;
  const int h = l >> 5, w = l & 31;
  float acc = 0.f;
  for (int i = 0; i < CIN; ++i)
    for (int kk = 0; kk < 9; ++kk) {
      const int yy = h + kk / 3 - 1, xx = w + kk % 3 - 1;
      const float v = (yy >= 0 && yy < 32 && xx >= 0 && xx < 32)
                          ? x[((b * CIN + i) * 32 + yy) * 32 + xx] : 0.f;
      float ftr[9];
      basis9(v, ftr);
      const int base = (i * COUT + o) * 9 + kk;
      const float* cp = cc + base * 8;
      float dot = 0.f;
#pragma unroll
      for (int f = 0; f < 8; ++f) dot += cp[f] * ftr[f];
      acc += wsp[base] * dot + wb[base] * ftr[8];
    }
  out[idx] = acc;
}

extern "C" void kernel_launch(void* const* d_in, const int* in_sizes, int n_in,
                              void* d_out, int out_size, void* d_ws, size_t ws_size,
                              hipStream_t stream) {
  const float* x  = (const float*)d_in[0];
  const float* wb = (const float*)d_in[1];
  const float* wsp = (const float*)d_in[2];
  const float* cc = (const float*)d_in[3];
  float* out = (float*)d_out;

  if (ws_size < WS_NEED2) {
    naive_kernel<<<(BATCH * COUT * LPIX + 255) / 256, 256, 0, stream>>>(x, wb, wsp, cc, out);
    return;
  }

  char* ws = (char*)d_ws;
  ushort_t* feat = (ushort_t*)ws;
  ushort_t* W    = (ushort_t*)(ws + W_OFF);
  float* part    = (float*)(ws + PART_OFF);

  feat_kernel<<<PIXN / 4, 256, 0, stream>>>(x, feat);
  prep_w_kernel<<<(COUT * KTOT) / 256, 256, 0, stream>>>(wb, wsp, cc, W);
  if (ws_size >= WS_NEED4) {
    gemm_kernel<4><<<128 * 4, 256, 0, stream>>>(feat, W, out, part);
    add_kernel<3><<<PART_ELEMS / 1024, 256, 0, stream>>>(out, part);
  } else {
    gemm_kernel<2><<<128 * 2, 256, 0, stream>>>(feat, W, out, part);
    add_kernel<1><<<PART_ELEMS / 1024, 256, 0, stream>>>(out, part);
  }
}